// Round 3
// baseline (1722.245 us; speedup 1.0000x reference)
//
#include <hip/hip_runtime.h>
#include <cstdint>
#include <cstddef>

#define U_CNT 100000
#define I_CNT 50000
#define D_DIM 64
#define N_CNT (U_CNT + I_CNT)
#define NNZ_CNT 4000000
#define EPS_F 0.2f

// Column-bucketed CSR: key = row*NB + col/CHUNK. The persistent layer kernel
// sweeps buckets 0..15; because the whole grid is co-resident and starts
// together, all waves gather from the same ~2.4MB x-window per phase
// (fits each XCD's 4MiB L2). No barrier: drift is bounded by work variance.
#define NB 16
#define CHUNK ((N_CNT + NB - 1) / NB)                    // 9375 cols = 2.4 MB of x
#define M_CNT (N_CNT * NB)                               // 2,400,000 keys
#define SCAN_TILE 1024
#define N_TILES2 ((M_CNT + SCAN_TILE - 1) / SCAN_TILE)   // 2344
#define NROWSETS (N_CNT / 16)                            // 9375 row-sets of 16 (exact)
#define NSET 10                                          // row-sets per block
#define G_LAYER ((NROWSETS + NSET - 1) / NSET)           // 938 persistent blocks

// ---------------- CSR build: histogram over (row,bucket) keys ----------------
__global__ void hist_kernel(const int* __restrict__ rows, const int* __restrict__ cols,
                            int* __restrict__ deg) {
    int t = blockIdx.x * blockDim.x + threadIdx.x;
    if (t >= NNZ_CNT / 4) return;
    int4 r4 = ((const int4*)rows)[t];
    int4 c4 = ((const int4*)cols)[t];
    atomicAdd(&deg[r4.x * NB + c4.x / CHUNK], 1);
    atomicAdd(&deg[r4.y * NB + c4.y / CHUNK], 1);
    atomicAdd(&deg[r4.z * NB + c4.z / CHUNK], 1);
    atomicAdd(&deg[r4.w * NB + c4.w / CHUNK], 1);
}

// ---------------- scan stage 1: per-tile scan ----------------
// Writes tile-local exclusive scan into BOTH rowptr and deg (deg becomes the
// scatter cursor, pre-seeded with start offsets -> scatter needs no rowptr read).
__global__ __launch_bounds__(256) void partial_scan_kernel(
    int* __restrict__ deg, int* __restrict__ rowptr, int* __restrict__ tileSums) {
    __shared__ int lds[256];
    const int t = threadIdx.x;
    const int gbase = blockIdx.x * SCAN_TILE + t * 4;
    int v[4];
    int s = 0;
    #pragma unroll
    for (int j = 0; j < 4; ++j) {
        int i = gbase + j;
        v[j] = (i < M_CNT) ? deg[i] : 0;
        s += v[j];
    }
    lds[t] = s;
    __syncthreads();
    for (int off = 1; off < 256; off <<= 1) {
        int x = (t >= off) ? lds[t - off] : 0;
        __syncthreads();
        lds[t] += x;
        __syncthreads();
    }
    int ex = (t > 0) ? lds[t - 1] : 0;
    #pragma unroll
    for (int j = 0; j < 4; ++j) {
        int i = gbase + j;
        if (i < M_CNT) { rowptr[i] = ex; deg[i] = ex; }
        ex += v[j];
    }
    if (t == 255) tileSums[blockIdx.x] = lds[255];
}

// ---------------- scan stage 2: scan tile sums (2344, single block) ----------
__global__ __launch_bounds__(256) void scan_sums_kernel(
    const int* __restrict__ tileSums, int* __restrict__ tileOffs,
    int* __restrict__ rowptr) {
    __shared__ int lds[256];
    const int t = threadIdx.x;
    int carry = 0;
    for (int base = 0; base < N_TILES2; base += SCAN_TILE) {
        int v[4];
        int s = 0;
        #pragma unroll
        for (int j = 0; j < 4; ++j) {
            int i = base + t * 4 + j;
            v[j] = (i < N_TILES2) ? tileSums[i] : 0;
            s += v[j];
        }
        lds[t] = s;
        __syncthreads();
        for (int off = 1; off < 256; off <<= 1) {
            int x = (t >= off) ? lds[t - off] : 0;
            __syncthreads();
            lds[t] += x;
            __syncthreads();
        }
        int ex = carry + ((t > 0) ? lds[t - 1] : 0);
        #pragma unroll
        for (int j = 0; j < 4; ++j) {
            int i = base + t * 4 + j;
            if (i < N_TILES2) tileOffs[i] = ex;
            ex += v[j];
        }
        carry += lds[255];
        __syncthreads();
    }
    if (t == 0) rowptr[M_CNT] = carry;
}

// ---------------- scan stage 3: add tile offsets to rowptr AND cursor --------
__global__ __launch_bounds__(256) void add_offs_kernel(
    int* __restrict__ rowptr, int* __restrict__ deg, const int* __restrict__ tileOffs) {
    const int off = tileOffs[blockIdx.x];
    const int gbase = blockIdx.x * SCAN_TILE + threadIdx.x * 4;
    #pragma unroll
    for (int j = 0; j < 4; ++j) {
        int i = gbase + j;
        if (i < M_CNT) { rowptr[i] += off; deg[i] += off; }
    }
}

// ---------------- CSR build: scatter via pre-seeded cursor ----------
__global__ void scatter_kernel(const int* __restrict__ rows, const int* __restrict__ cols,
                               const float* __restrict__ vals,
                               int* __restrict__ cursor, int2* __restrict__ cpack) {
    int t = blockIdx.x * blockDim.x + threadIdx.x;
    if (t >= NNZ_CNT / 4) return;
    int4   r4 = ((const int4*)rows)[t];
    int4   c4 = ((const int4*)cols)[t];
    float4 v4 = ((const float4*)vals)[t];
    int p;
    p = atomicAdd(&cursor[r4.x * NB + c4.x / CHUNK], 1); cpack[p] = make_int2(c4.x, __float_as_int(v4.x));
    p = atomicAdd(&cursor[r4.y * NB + c4.y / CHUNK], 1); cpack[p] = make_int2(c4.y, __float_as_int(v4.y));
    p = atomicAdd(&cursor[r4.z * NB + c4.z / CHUNK], 1); cpack[p] = make_int2(c4.z, __float_as_int(v4.z));
    p = atomicAdd(&cursor[r4.w * NB + c4.w / CHUNK], 1); cpack[p] = make_int2(c4.w, __float_as_int(v4.w));
}

__device__ __forceinline__ float sgnf(float x) {
    return (x > 0.f) ? 1.f : ((x < 0.f) ? -1.f : 0.f);
}

// ---------------- persistent phase-swept SpMM layer -------------
// 938 blocks, 4 blocks/CU max via __launch_bounds__(256,4) -> whole grid
// co-resident and starts the bucket sweep simultaneously. Each block owns
// NSET=10 contiguous row-sets of 16 rows; acc stays in registers (40 VGPR).
// MODE 0: gather (ue,ie) split; xnext = ego; acc_out = ego
// MODE 1: gather xin;          xnext = ego; acc_out += ego
// MODE 2: gather xin;          acc_out = (acc_out + ego)/3
template <int MODE>
__global__ __launch_bounds__(256, 4) void layer_persist_kernel(
    const int* __restrict__ rowptr, const int2* __restrict__ cpack,
    const float4* __restrict__ xin, const float4* __restrict__ ue4,
    const float4* __restrict__ ie4,
    const float4* __restrict__ noise_k, float4* __restrict__ xnext,
    float4* __restrict__ acc_out) {
    const int gl  = threadIdx.x & 15;           // lane within 16-lane row group
    const int sub = threadIdx.x >> 4;           // row group within block (0..15)
    const int bid = blockIdx.x;

    float4 acc[NSET];
    #pragma unroll
    for (int s = 0; s < NSET; ++s) acc[s] = make_float4(0.f, 0.f, 0.f, 0.f);

    for (int ph = 0; ph < NB; ++ph) {
        #pragma unroll
        for (int s = 0; s < NSET; ++s) {      // compile-time acc index (no scratch)
            const int rs = bid * NSET + s;
            if (rs < NROWSETS) {
                const int r = rs * 16 + sub;
                const int base = r * NB + ph;
                const int e0 = rowptr[base];
                const int e1 = rowptr[base + 1];
                float4 a = acc[s];
                #pragma unroll 4
                for (int e = e0; e < e1; ++e) {
                    int2 p = cpack[e];                    // group-uniform 8B load
                    float vj = __int_as_float(p.y);
                    const float4* xb;
                    if (MODE == 0) {
                        xb = (p.x < U_CNT) ? (ue4 + (size_t)p.x * 16)
                                           : (ie4 + (size_t)(p.x - U_CNT) * 16);
                    } else {
                        xb = xin + (size_t)p.x * 16;
                    }
                    float4 xr = xb[gl];                   // 256B/row over 16 lanes
                    a.x += vj * xr.x;
                    a.y += vj * xr.y;
                    a.z += vj * xr.z;
                    a.w += vj * xr.w;
                }
                acc[s] = a;
            }
        }
    }

    // epilogue: noise + outputs, per owned row-set
    #pragma unroll
    for (int s = 0; s < NSET; ++s) {
        const int rs = bid * NSET + s;
        if (rs < NROWSETS) {
            const int r = rs * 16 + sub;
            float4 nz = noise_k[(size_t)r * 16 + gl];
            float sq = nz.x * nz.x + nz.y * nz.y + nz.z * nz.z + nz.w * nz.w;
            #pragma unroll
            for (int off = 8; off > 0; off >>= 1) sq += __shfl_xor(sq, off);
            float inv = EPS_F / fmaxf(sqrtf(sq), 1e-12f);

            float4 a = acc[s];
            float4 ego;
            ego.x = a.x + sgnf(a.x) * nz.x * inv;
            ego.y = a.y + sgnf(a.y) * nz.y * inv;
            ego.z = a.z + sgnf(a.z) * nz.z * inv;
            ego.w = a.w + sgnf(a.w) * nz.w * inv;

            size_t oi = (size_t)r * 16 + gl;
            if (MODE == 0) {
                xnext[oi] = ego;
                acc_out[oi] = ego;
            } else if (MODE == 1) {
                xnext[oi] = ego;
                float4 o = acc_out[oi];
                o.x += ego.x; o.y += ego.y; o.z += ego.z; o.w += ego.w;
                acc_out[oi] = o;
            } else {
                float4 o = acc_out[oi];
                o.x = (o.x + ego.x) * (1.f / 3.f);
                o.y = (o.y + ego.y) * (1.f / 3.f);
                o.z = (o.z + ego.z) * (1.f / 3.f);
                o.w = (o.w + ego.w) * (1.f / 3.f);
                acc_out[oi] = o;
            }
        }
    }
}

extern "C" void kernel_launch(void* const* d_in, const int* in_sizes, int n_in,
                              void* d_out, int out_size, void* d_ws, size_t ws_size,
                              hipStream_t stream) {
    const float* ue    = (const float*)d_in[0];
    const float* ie    = (const float*)d_in[1];
    const int*   rows  = (const int*)d_in[2];
    const int*   cols  = (const int*)d_in[3];
    const float* vals  = (const float*)d_in[4];
    const float* noise = (const float*)d_in[5];
    float* out = (float*)d_out;
    char*  ws  = (char*)d_ws;

    auto align16 = [](size_t x) { return (x + 15) & ~(size_t)15; };
    size_t off = 0;
    int*   rowptr2  = (int*)(ws + off);  off = align16(off + (size_t)(M_CNT + 1) * 4);
    int*   tileSums = (int*)(ws + off);  off = align16(off + (size_t)N_TILES2 * 4);
    int*   tileOffs = (int*)(ws + off);  off = align16(off + (size_t)N_TILES2 * 4);
    int2*  cpack    = (int2*)(ws + off); off = align16(off + (size_t)NNZ_CNT * 8);
    float* bufA     = (float*)(ws + off); off += (size_t)N_CNT * D_DIM * 4;
    // deg/cursor (9.6 MB) aliases bufA: build completes before layer 1 writes bufA.
    int*   deg2     = (int*)bufA;
    (void)ws_size; (void)in_sizes; (void)n_in; (void)out_size;

    const size_t ND = (size_t)N_CNT * D_DIM;
    float* cl = out + ND;  // ego_cl region; doubles as layer-0 output / layer-1 input

    // ---- CSR build (bucketed keys, cursor pre-seeded with scan) ----
    hipMemsetAsync(deg2, 0, (size_t)M_CNT * 4, stream);
    hist_kernel<<<(NNZ_CNT / 4 + 255) / 256, 256, 0, stream>>>(rows, cols, deg2);
    partial_scan_kernel<<<N_TILES2, 256, 0, stream>>>(deg2, rowptr2, tileSums);
    scan_sums_kernel<<<1, 256, 0, stream>>>(tileSums, tileOffs, rowptr2);
    add_offs_kernel<<<N_TILES2, 256, 0, stream>>>(rowptr2, deg2, tileOffs);
    scatter_kernel<<<(NNZ_CNT / 4 + 255) / 256, 256, 0, stream>>>(rows, cols, vals,
                                                                  deg2, cpack);

    // ---- 3 persistent phase-swept propagation layers ----
    layer_persist_kernel<0><<<G_LAYER, 256, 0, stream>>>(
        rowptr2, cpack, nullptr, (const float4*)ue, (const float4*)ie,
        (const float4*)(noise + 0 * ND), (float4*)cl, (float4*)out);
    layer_persist_kernel<1><<<G_LAYER, 256, 0, stream>>>(
        rowptr2, cpack, (const float4*)cl, nullptr, nullptr,
        (const float4*)(noise + 1 * ND), (float4*)bufA, (float4*)out);
    layer_persist_kernel<2><<<G_LAYER, 256, 0, stream>>>(
        rowptr2, cpack, (const float4*)bufA, nullptr, nullptr,
        (const float4*)(noise + 2 * ND), nullptr, (float4*)out);
}